// Round 1
// baseline (285.856 us; speedup 1.0000x reference)
//
#include <hip/hip_runtime.h>

// ---------- helpers ----------
__device__ __forceinline__ unsigned short f2b(float f) {
    unsigned int u = __builtin_bit_cast(unsigned int, f);
    unsigned int r = (u + 0x7FFFu + ((u >> 16) & 1u)) >> 16;  // RNE
    return (unsigned short)r;
}
__device__ __forceinline__ float b2f(unsigned short s) {
    unsigned int u = ((unsigned int)s) << 16;
    return __builtin_bit_cast(float, u);
}

typedef __attribute__((ext_vector_type(8))) short short8;
typedef __attribute__((ext_vector_type(4))) float float4v;

#define GLD16(g, l) __builtin_amdgcn_global_load_lds(                          \
    (const __attribute__((address_space(1))) unsigned int*)(g),                \
    (__attribute__((address_space(3))) unsigned int*)(l), 16, 0, 0)

// L=16384, D_IN=512, D_H=1024, D_OUT=512
#define SEQLEN 16384
#define NCHUNK 256
#define TCHUNK 64

// ---------- x (f32) -> bf16 into Hcat cols [2048,2560) ----------
__global__ void xcast(const float* __restrict__ x, unsigned short* __restrict__ Hcat) {
    int id = blockIdx.x * 256 + threadIdx.x;      // one per 4 elements
    int t = id >> 7;                               // 128 float4 per row
    int k4 = (id & 127) << 2;
    float4 v = *(const float4*)(x + (long)t * 512 + k4);
    ushort4 o;
    o.x = f2b(v.x); o.y = f2b(v.y); o.z = f2b(v.z); o.w = f2b(v.w);
    *(ushort4*)(Hcat + (long)t * 2560 + 2048 + k4) = o;
}

// ---------- Bcat[n,k] = e^gamma[n%1024] * (n<1024 ? B_re : B_im)[n%1024, k], bf16 ----------
__global__ void prep_B(const float* __restrict__ B_re, const float* __restrict__ B_im,
                       const float* __restrict__ gamma, unsigned short* __restrict__ Bcat) {
    int id = blockIdx.x * 256 + threadIdx.x;      // one per 4 elements of [2048 x 512]
    int n = id >> 7;
    int k4 = (id & 127) << 2;
    const float* src = (n < 1024) ? (B_re + (long)n * 512) : (B_im + (long)(n - 1024) * 512);
    float g = expf(gamma[n & 1023]);
    float4 v = *(const float4*)(src + k4);
    ushort4 o;
    o.x = f2b(v.x * g); o.y = f2b(v.y * g); o.z = f2b(v.z * g); o.w = f2b(v.w * g);
    *(ushort4*)(Bcat + (long)n * 512 + k4) = o;
}

// ---------- CW[o,j]: j<1024 -> C_re, j<2048 -> -C_im, else D. bf16 [512 x 2560] ----------
__global__ void prep_CW(const float* __restrict__ C_re, const float* __restrict__ C_im,
                        const float* __restrict__ Dm, unsigned short* __restrict__ CW) {
    int id = blockIdx.x * 256 + threadIdx.x;      // one per 4 elements of [512 x 2560]
    int o = id / 640;
    int j4 = (id - o * 640) << 2;
    float4 v; float sgn = 1.0f;
    if (j4 < 1024) {
        v = *(const float4*)(C_re + (long)o * 1024 + j4);
    } else if (j4 < 2048) {
        v = *(const float4*)(C_im + (long)o * 1024 + (j4 - 1024));
        sgn = -1.0f;
    } else {
        v = *(const float4*)(Dm + (long)o * 512 + (j4 - 2048));
    }
    ushort4 w;
    w.x = f2b(v.x * sgn); w.y = f2b(v.y * sgn); w.z = f2b(v.z * sgn); w.w = f2b(v.w * sgn);
    *(ushort4*)(CW + (long)o * 2560 + j4) = w;
}

// ---------- m97-style bf16 GEMM, A[M x lda] (rows m, cols K), B[N x ldb] (rows n, cols K) ----------
// C[m,n] = sum_k A[m,k]*B[n,k].  128x128 tile, BK=32, 256 threads (4 waves, 64x64 each).
template <bool OUT_BF16>
__launch_bounds__(256)
__global__ void gemm_bt(const unsigned short* __restrict__ A, int lda,
                        const unsigned short* __restrict__ B, int ldb,
                        void* __restrict__ Cout, int ldc, int Ktot) {
    __shared__ unsigned short As[128 * 32] __attribute__((aligned(16)));
    __shared__ unsigned short Bs[128 * 32] __attribute__((aligned(16)));
    const int tid = threadIdx.x;
    const int wave = tid >> 6;
    const int lane = tid & 63;
    const long m0 = (long)blockIdx.y * 128;
    const long n0 = (long)blockIdx.x * 128;
    const int wm = (wave >> 1) * 64;
    const int wn = (wave & 1) * 64;

    // staging: segment s in [0,512): row = s>>2, col8 = (s&3)*8;  two calls per tile per thread
    const int s1 = wave * 64 + lane;
    const int r1 = s1 >> 2, c1 = (s1 & 3) * 8;
    const int s2 = s1 + 256;
    const int r2 = s2 >> 2, c2 = (s2 & 3) * 8;
    const unsigned short* Arow1 = A + (m0 + r1) * lda + c1;
    const unsigned short* Arow2 = A + (m0 + r2) * lda + c2;
    const unsigned short* Brow1 = B + (n0 + r1) * ldb + c1;
    const unsigned short* Brow2 = B + (n0 + r2) * ldb + c2;
    char* AsB1 = (char*)As + wave * 1024;
    char* AsB2 = (char*)As + 4096 + wave * 1024;
    char* BsB1 = (char*)Bs + wave * 1024;
    char* BsB2 = (char*)Bs + 4096 + wave * 1024;

    const int fr = lane & 15;          // fragment row (m or n)
    const int fk = (lane >> 4) * 8;    // fragment k start within BK=32

    float4v acc[4][4] = {};

    for (int k0 = 0; k0 < Ktot; k0 += 32) {
        GLD16(Arow1 + k0, AsB1);
        GLD16(Arow2 + k0, AsB2);
        GLD16(Brow1 + k0, BsB1);
        GLD16(Brow2 + k0, BsB2);
        __syncthreads();
        short8 af[4], bfr[4];
#pragma unroll
        for (int i = 0; i < 4; i++) {
            af[i]  = *(const short8*)(As + (wm + i * 16 + fr) * 32 + fk);
            bfr[i] = *(const short8*)(Bs + (wn + i * 16 + fr) * 32 + fk);
        }
#pragma unroll
        for (int mi = 0; mi < 4; mi++)
#pragma unroll
            for (int ni = 0; ni < 4; ni++)
                acc[mi][ni] = __builtin_amdgcn_mfma_f32_16x16x32_bf16(af[mi], bfr[ni], acc[mi][ni], 0, 0, 0);
        __syncthreads();
    }

    // epilogue: C/D layout col=lane&15, row=(lane>>4)*4+reg
    const int er = (lane >> 4) * 4;
    const int ec = lane & 15;
#pragma unroll
    for (int mi = 0; mi < 4; mi++) {
#pragma unroll
        for (int r = 0; r < 4; r++) {
            long grow = m0 + wm + mi * 16 + er + r;
#pragma unroll
            for (int ni = 0; ni < 4; ni++) {
                long gcol = n0 + wn + ni * 16 + ec;
                float v = acc[mi][ni][r];
                if (OUT_BF16)
                    ((unsigned short*)Cout)[grow * ldc + gcol] = f2b(v);
                else
                    ((float*)Cout)[grow * ldc + gcol] = v;
            }
        }
    }
}

// ---------- scan pass B: per-chunk local end states (zero-init) ----------
// Bu [L, 2048] bf16 (re cols 0..1023, im 1024..2047). E [NCHUNK, 2048] f32.
__global__ void scan_ends(const unsigned short* __restrict__ Bu,
                          const float* __restrict__ lamb,
                          float* __restrict__ E) {
    const int chunk = blockIdx.x;
    const int ch = threadIdx.x << 2;   // 4 channels per thread
    float lre[4], lim[4];
#pragma unroll
    for (int i = 0; i < 4; i++) {
        float nu = expf(-expf(lamb[ch + i]));
        float th = expf(lamb[1024 + ch + i]);
        lre[i] = nu * cosf(th);
        lim[i] = nu * sinf(th);
    }
    float hr[4] = {0, 0, 0, 0}, hi[4] = {0, 0, 0, 0};
    const unsigned short* base = Bu + (long)chunk * TCHUNK * 2048 + ch;
#pragma unroll 4
    for (int t = 0; t < TCHUNK; t++) {
        ushort4 br = *(const ushort4*)(base + (long)t * 2048);
        ushort4 bi = *(const ushort4*)(base + (long)t * 2048 + 1024);
        float brf[4] = {b2f(br.x), b2f(br.y), b2f(br.z), b2f(br.w)};
        float bif[4] = {b2f(bi.x), b2f(bi.y), b2f(bi.z), b2f(bi.w)};
#pragma unroll
        for (int i = 0; i < 4; i++) {
            float nr = fmaf(lre[i], hr[i], fmaf(-lim[i], hi[i], brf[i]));
            float ni = fmaf(lre[i], hi[i], fmaf(lim[i], hr[i], bif[i]));
            hr[i] = nr; hi[i] = ni;
        }
    }
    float* Ec = E + (long)chunk * 2048 + ch;
#pragma unroll
    for (int i = 0; i < 4; i++) {
        Ec[i] = hr[i];
        Ec[1024 + i] = hi[i];
    }
}

// ---------- scan pass C: sequential carry combine over chunks ----------
// Kc[c] = global state BEFORE chunk c.  H_c = lam^T * H_{c-1} + E_c.
__global__ void carry(const float* __restrict__ lamb, const float* __restrict__ E,
                      float* __restrict__ Kc) {
    const int ch = blockIdx.x * 256 + threadIdx.x;  // 0..1023
    double nu = exp(-exp((double)lamb[ch]));
    double th = exp((double)lamb[1024 + ch]);
    double lr = nu * cos(th), li = nu * sin(th);
    // lambda^64 via 6 squarings (double)
#pragma unroll
    for (int i = 0; i < 6; i++) {
        double rr = lr * lr - li * li;
        double ii = 2.0 * lr * li;
        lr = rr; li = ii;
    }
    float tre = (float)lr, tim = (float)li;
    float hr = 0.0f, hi = 0.0f;
#pragma unroll 8
    for (int c = 0; c < NCHUNK; c++) {
        Kc[(long)c * 2048 + ch] = hr;
        Kc[(long)c * 2048 + 1024 + ch] = hi;
        float er = E[(long)c * 2048 + ch];
        float ei = E[(long)c * 2048 + 1024 + ch];
        float nr = fmaf(tre, hr, fmaf(-tim, hi, er));
        float ni = fmaf(tre, hi, fmaf(tim, hr, ei));
        hr = nr; hi = ni;
    }
}

// ---------- scan pass D: re-scan each chunk seeded with carry; emit h bf16 into Hcat ----------
__global__ void scan_apply(const unsigned short* __restrict__ Bu,
                           const float* __restrict__ lamb,
                           const float* __restrict__ Kc,
                           unsigned short* __restrict__ Hcat) {
    const int chunk = blockIdx.x;
    const int ch = threadIdx.x << 2;
    float lre[4], lim[4];
#pragma unroll
    for (int i = 0; i < 4; i++) {
        float nu = expf(-expf(lamb[ch + i]));
        float th = expf(lamb[1024 + ch + i]);
        lre[i] = nu * cosf(th);
        lim[i] = nu * sinf(th);
    }
    float hr[4], hi[4];
#pragma unroll
    for (int i = 0; i < 4; i++) {
        hr[i] = Kc[(long)chunk * 2048 + ch + i];
        hi[i] = Kc[(long)chunk * 2048 + 1024 + ch + i];
    }
    const unsigned short* base = Bu + (long)chunk * TCHUNK * 2048 + ch;
    unsigned short* Hc = Hcat + (long)chunk * TCHUNK * 2560 + ch;
#pragma unroll 4
    for (int t = 0; t < TCHUNK; t++) {
        ushort4 br = *(const ushort4*)(base + (long)t * 2048);
        ushort4 bi = *(const ushort4*)(base + (long)t * 2048 + 1024);
        float brf[4] = {b2f(br.x), b2f(br.y), b2f(br.z), b2f(br.w)};
        float bif[4] = {b2f(bi.x), b2f(bi.y), b2f(bi.z), b2f(bi.w)};
#pragma unroll
        for (int i = 0; i < 4; i++) {
            float nr = fmaf(lre[i], hr[i], fmaf(-lim[i], hi[i], brf[i]));
            float ni = fmaf(lre[i], hi[i], fmaf(lim[i], hr[i], bif[i]));
            hr[i] = nr; hi[i] = ni;
        }
        ushort4 orv, oiv;
        orv.x = f2b(hr[0]); orv.y = f2b(hr[1]); orv.z = f2b(hr[2]); orv.w = f2b(hr[3]);
        oiv.x = f2b(hi[0]); oiv.y = f2b(hi[1]); oiv.z = f2b(hi[2]); oiv.w = f2b(hi[3]);
        *(ushort4*)(Hc + (long)t * 2560) = orv;
        *(ushort4*)(Hc + (long)t * 2560 + 1024) = oiv;
    }
}

// ---------- launch ----------
extern "C" void kernel_launch(void* const* d_in, const int* in_sizes, int n_in,
                              void* d_out, int out_size, void* d_ws, size_t ws_size,
                              hipStream_t stream) {
    const float* x     = (const float*)d_in[0];  // [16384, 512]
    const float* lamb  = (const float*)d_in[1];  // [2, 1024]
    const float* gamma = (const float*)d_in[2];  // [1024]
    const float* B_re  = (const float*)d_in[3];  // [1024, 512]
    const float* B_im  = (const float*)d_in[4];
    const float* C_re  = (const float*)d_in[5];  // [512, 1024]
    const float* C_im  = (const float*)d_in[6];
    const float* Dm    = (const float*)d_in[7];  // [512, 512]

    char* ws = (char*)d_ws;
    unsigned short* Bu   = (unsigned short*)ws;                              // 16384*2048*2 = 67108864
    unsigned short* Hcat = (unsigned short*)(ws + 67108864);                 // 16384*2560*2 = 83886080
    float* E  = (float*)(ws + 67108864 + 83886080);                          // 256*2048*4 = 2097152
    float* Kc = E + (long)NCHUNK * 2048;                                     // 2097152
    unsigned short* Bcat = (unsigned short*)((char*)Kc + 2097152);           // 2048*512*2 = 2097152
    unsigned short* CW   = Bcat + (long)2048 * 512;                          // 512*2560*2 = 2621440

    xcast<<<8192, 256, 0, stream>>>(x, Hcat);
    prep_B<<<1024, 256, 0, stream>>>(B_re, B_im, gamma, Bcat);
    prep_CW<<<1280, 256, 0, stream>>>(C_re, C_im, Dm, CW);
    // Bu = x_bf16 @ Bcat^T : [16384,512] x [2048,512]^T -> [16384,2048] bf16
    gemm_bt<true><<<dim3(16, 128), 256, 0, stream>>>(Hcat + 2048, 2560, Bcat, 512, Bu, 2048, 512);
    scan_ends<<<NCHUNK, 256, 0, stream>>>(Bu, lamb, E);
    carry<<<4, 256, 0, stream>>>(lamb, E, Kc);
    scan_apply<<<NCHUNK, 256, 0, stream>>>(Bu, lamb, Kc, Hcat);
    // y = Hcat @ CW^T : [16384,2560] x [512,2560]^T -> [16384,512] f32
    gemm_bt<false><<<dim3(4, 128), 256, 0, stream>>>(Hcat, 2560, CW, 2560, d_out, 512, 2560);
}